// Round 12
// baseline (234.635 us; speedup 1.0000x reference)
//
#include <hip/hip_runtime.h>
#include <hip/hip_bf16.h>

#define DIMN 2048
#define NQKV 6144
#define NH 16
#define HD 128
#define BSZ 2
#define SEQ 2048
#define ROWS (BSZ*SEQ)   // 4096

typedef short short8 __attribute__((ext_vector_type(8)));
typedef float f32x4 __attribute__((ext_vector_type(4)));

__device__ __forceinline__ unsigned short f2bf(float f) {
    __hip_bfloat16 h = __float2bfloat16(f);
    unsigned short u; __builtin_memcpy(&u, &h, 2); return u;
}

__device__ __forceinline__ void gld_lds16(const void* g, void* l) {
    __builtin_amdgcn_global_load_lds(
        (const __attribute__((address_space(1))) void*)g,
        (__attribute__((address_space(3))) void*)l, 16, 0, 0);
}

// ---------------- fused f32 -> bf16 converts ----------------
__global__ void cvt_all(const float* __restrict__ x, const float* __restrict__ wq,
                        const float* __restrict__ wk, const float* __restrict__ wv,
                        const float* __restrict__ wo,
                        unsigned short* __restrict__ Xb, unsigned short* __restrict__ Wcat,
                        unsigned short* __restrict__ Wo2) {
    int bid = blockIdx.x;
    const float* in; unsigned short* out; int base;
    if      (bid <  8192) { in = x;  out = Xb;             base = bid; }
    else if (bid < 12288) { in = wq; out = Wcat;           base = bid - 8192; }
    else if (bid < 16384) { in = wk; out = Wcat + 4194304; base = bid - 12288; }
    else if (bid < 20480) { in = wv; out = Wcat + 8388608; base = bid - 16384; }
    else                  { in = wo; out = Wo2;            base = bid - 20480; }
    int i = (base * 256 + threadIdx.x) * 4;
    float4 v = *(const float4*)(in + i);
    ushort4 o; o.x = f2bf(v.x); o.y = f2bf(v.y); o.z = f2bf(v.z); o.w = f2bf(v.w);
    *(ushort4*)(out + i) = o;
}

// ================= m97-style 128x128 GEMM + swizzle: C[m][n] = sum_k A[m][k]*B[n][k] =====
// r12 rationale: the 256x256 engine is locked to 1 block/CU (128KB LDS + 128 AGPR acc) so
// barrier drains are never covered (six schedules all ~700 TF). The m97 structure (128^2,
// BK=64, 256 thr, single-buffer 2-barrier loop) runs 3 blocks/CU: other blocks' waves cover
// each block's drain (m114). r1 was this structure at 576 TF WITH 1.26e7 16-way LDS read
// conflicts; this version adds the (verified, r6-r11) swizzle: physical col16 = logical ^
// (row&7), staged via pre-swizzled global source so the gld_lds dest stays linear.
// MODE 0: bf16 out + QKV region bias + fused RoPE.  MODE 1: f32 out + bias, B per batch.

template<int MODE>
__global__ __launch_bounds__(256) void gemm97(
    const unsigned short* __restrict__ A, int lda,
    const unsigned short* __restrict__ B, int ldb,
    const float* __restrict__ b0, const float* __restrict__ b1, const float* __restrict__ b2,
    const float* __restrict__ fcos, const float* __restrict__ fsin,
    void* __restrict__ C, int ldc, int K)
{
    __shared__ __align__(16) unsigned short As[128 * 64];  // 16 KB
    __shared__ __align__(16) unsigned short Bs[128 * 64];  // 16 KB

    const int t  = threadIdx.x;
    const int l  = t & 63;
    const int w  = t >> 6;
    const int wr = w >> 1, wc = w & 1;
    const int fr = l & 15, fq = l >> 4;

    // chunked XCD map: each XCD owns an n-stripe (B panel L2-resident: 3MB / 1MB)
    const int xcd = blockIdx.x & 7;
    const int j   = blockIdx.x >> 3;
    int mt, nt;
    if (MODE == 0) { nt = xcd * 6 + j % 6; mt = j / 6; }   // 48 nt x 32 mt, 1536 blocks
    else           { nt = xcd * 2 + (j & 1); mt = j >> 1; } // 16 nt x 32 mt, 512 blocks
    const int m0 = mt * 128;
    const int n0 = nt * 128;

    const unsigned short* Bsel = B;
    if (MODE == 1 && m0 >= 2048) Bsel += (size_t)2048 * 2048;  // per-batch W2

    // staging source: thread t covers row srow (+32/round), col16 sc; source col
    // pre-swizzled so the LINEAR gld_lds dest holds logical col (sc ^ (row&7)).
    const int srow = t >> 3;                         // 0..31
    const int sc   = t & 7;
    const int scol = (sc ^ (srow & 7)) * 8;
    const unsigned short* aS = A    + (size_t)(m0 + srow) * lda + scol;
    const unsigned short* bS = Bsel + (size_t)(n0 + srow) * ldb + scol;

    f32x4 acc[4][4] = {};

    for (int k0 = 0; k0 < K; k0 += 64) {
        __syncthreads();   // WAR: previous iteration's reads done
        #pragma unroll
        for (int r = 0; r < 4; ++r) {
            gld_lds16(aS + (size_t)(r * 32) * lda + k0, &As[r * 2048 + t * 8]);
            gld_lds16(bS + (size_t)(r * 32) * ldb + k0, &Bs[r * 2048 + t * 8]);
        }
        __syncthreads();   // compiler drains vmcnt(0) before barrier: data visible
        #pragma unroll
        for (int kk = 0; kk < 2; ++kk) {
            const int co = (((kk << 2) | fq) ^ (fr & 7)) * 8;   // swizzled col offset
            short8 a[4], b[4];
            #pragma unroll
            for (int mi = 0; mi < 4; ++mi)
                a[mi] = *(const short8*)&As[(wr * 64 + mi * 16 + fr) * 64 + co];
            #pragma unroll
            for (int ni = 0; ni < 4; ++ni)
                b[ni] = *(const short8*)&Bs[(wc * 64 + ni * 16 + fr) * 64 + co];
            #pragma unroll
            for (int mi = 0; mi < 4; ++mi)
                #pragma unroll
                for (int ni = 0; ni < 4; ++ni)
                    acc[mi][ni] = __builtin_amdgcn_mfma_f32_16x16x32_bf16(a[mi], b[ni], acc[mi][ni], 0, 0, 0);
        }
    }

    // ---- epilogue: bias (+ RoPE for MODE 0 on cols < 4096), store
    #pragma unroll
    for (int mi = 0; mi < 4; ++mi) {
        #pragma unroll
        for (int ni = 0; ni < 4; ++ni) {
            #pragma unroll
            for (int j2 = 0; j2 < 4; ++j2) {
                const int r  = m0 + wr * 64 + mi * 16 + fq * 4 + j2;
                const int cg = n0 + wc * 64 + ni * 16 + fr;
                float v = acc[mi][ni][j2];
                if (MODE == 0) {
                    v += (cg < 2048) ? b0[cg] : ((cg < 4096) ? b1[cg - 2048] : b2[cg - 4096]);
                    if (cg < 4096) {  // block-uniform branch: RoPE on Q and K
                        const int s = r & (SEQ - 1);
                        const int i = (cg >> 1) & 63;
                        const float cs = fcos[s * 64 + i];
                        const float sn = fsin[s * 64 + i];
                        const float p  = __shfl_xor(v, 1);
                        v = (fr & 1) ? (p * sn + v * cs) : (v * cs - p * sn);
                    }
                    ((unsigned short*)C)[(size_t)r * ldc + cg] = f2bf(v);
                } else {
                    v += b0[cg];
                    ((float*)C)[(size_t)r * ldc + cg] = v;
                }
            }
        }
    }
}

// ---------------- 128x128 GEMM core (small GEMMs) ----------------
template<int OUT_BF16, int HAS_BIAS>
__device__ __forceinline__ void gemm_tile_core(
    const unsigned short* __restrict__ A, int lda,
    const unsigned short* __restrict__ B, int ldb,
    const float* __restrict__ bias,
    void* __restrict__ Cptr, int ldc, int K)
{
    __shared__ __align__(16) unsigned short As[128 * 64];
    __shared__ __align__(16) unsigned short Bs[128 * 64];

    const int t  = threadIdx.x;
    const int l  = t & 63;
    const int w  = t >> 6;
    const int wr = w >> 1, wc = w & 1;
    const int fr = l & 15, fq = l >> 4;

    f32x4 acc[4][4] = {};

    const int srow = t >> 3;
    const int scol = (t & 7) * 8;

    for (int k0 = 0; k0 < K; k0 += 64) {
        __syncthreads();
        #pragma unroll
        for (int r = 0; r < 4; ++r) {
            gld_lds16(A + (size_t)(r * 32 + srow) * lda + k0 + scol, &As[(r * 32 + srow) * 64 + scol]);
            gld_lds16(B + (size_t)(r * 32 + srow) * ldb + k0 + scol, &Bs[(r * 32 + srow) * 64 + scol]);
        }
        __syncthreads();
        #pragma unroll
        for (int kk = 0; kk < 2; ++kk) {
            short8 a[4], b[4];
            #pragma unroll
            for (int mi = 0; mi < 4; ++mi)
                a[mi] = *(const short8*)&As[(wr * 64 + mi * 16 + fr) * 64 + kk * 32 + fq * 8];
            #pragma unroll
            for (int ni = 0; ni < 4; ++ni)
                b[ni] = *(const short8*)&Bs[(wc * 64 + ni * 16 + fr) * 64 + kk * 32 + fq * 8];
            #pragma unroll
            for (int mi = 0; mi < 4; ++mi)
                #pragma unroll
                for (int ni = 0; ni < 4; ++ni)
                    acc[mi][ni] = __builtin_amdgcn_mfma_f32_16x16x32_bf16(a[mi], b[ni], acc[mi][ni], 0, 0, 0);
        }
    }

    #pragma unroll
    for (int mi = 0; mi < 4; ++mi) {
        #pragma unroll
        for (int ni = 0; ni < 4; ++ni) {
            #pragma unroll
            for (int j = 0; j < 4; ++j) {
                int rr = wr * 64 + mi * 16 + fq * 4 + j;
                int cc = wc * 64 + ni * 16 + fr;
                float v = acc[mi][ni][j];
                if (HAS_BIAS) v += bias[cc];
                if (OUT_BF16) ((unsigned short*)Cptr)[(size_t)rr * ldc + cc] = f2bf(v);
                else          ((float*)Cptr)[(size_t)rr * ldc + cc] = v;
            }
        }
    }
}

// ---------------- K^T/V partials ----------------
__global__ __launch_bounds__(256) void ktv_kernel(
    const unsigned short* __restrict__ QKV, float* __restrict__ part)
{
    const int ks = blockIdx.x;
    const int bh = blockIdx.y;
    const int b = bh >> 4, h = bh & 15;
    const unsigned short* Kbase = QKV + (size_t)(b * SEQ + ks * 256) * NQKV + 2048 + h * HD;
    const unsigned short* Vbase = QKV + (size_t)(b * SEQ + ks * 256) * NQKV + 4096 + h * HD;

    __shared__ __align__(16) unsigned short Ks_[64 * 128];
    __shared__ __align__(16) unsigned short Vs_[64 * 128];

    const int t  = threadIdx.x;
    const int l  = t & 63;
    const int w  = t >> 6;
    const int wr = w >> 1, wc = w & 1;
    const int fr = l & 15, fq = l >> 4;

    f32x4 acc[4][4] = {};

    const int srow = t >> 4;
    const int scol = (t & 15) * 8;

    for (int sc = 0; sc < 4; ++sc) {
        __syncthreads();
        #pragma unroll
        for (int r = 0; r < 4; ++r) {
            gld_lds16(Kbase + (size_t)(sc * 64 + r * 16 + srow) * NQKV + scol, &Ks_[(r * 16 + srow) * 128 + scol]);
            gld_lds16(Vbase + (size_t)(sc * 64 + r * 16 + srow) * NQKV + scol, &Vs_[(r * 16 + srow) * 128 + scol]);
        }
        __syncthreads();
        #pragma unroll
        for (int kk = 0; kk < 2; ++kk) {
            short8 a[4], bb[4];
            #pragma unroll
            for (int mi = 0; mi < 4; ++mi)
                #pragma unroll
                for (int i = 0; i < 8; ++i)
                    a[mi][i] = (short)Ks_[(kk * 32 + fq * 8 + i) * 128 + wr * 64 + mi * 16 + fr];
            #pragma unroll
            for (int ni = 0; ni < 4; ++ni)
                #pragma unroll
                for (int i = 0; i < 8; ++i)
                    bb[ni][i] = (short)Vs_[(kk * 32 + fq * 8 + i) * 128 + wc * 64 + ni * 16 + fr];
            #pragma unroll
            for (int mi = 0; mi < 4; ++mi)
                #pragma unroll
                for (int ni = 0; ni < 4; ++ni)
                    acc[mi][ni] = __builtin_amdgcn_mfma_f32_16x16x32_bf16(a[mi], bb[ni], acc[mi][ni], 0, 0, 0);
        }
    }

    float* base = part + ((size_t)bh * 8 + ks) * 16384;
    #pragma unroll
    for (int mi = 0; mi < 4; ++mi)
        #pragma unroll
        for (int ni = 0; ni < 4; ++ni)
            #pragma unroll
            for (int j = 0; j < 4; ++j)
                base[(wr * 64 + mi * 16 + fq * 4 + j) * 128 + wc * 64 + ni * 16 + fr] = acc[mi][ni][j];
}

// ---------------- reduce partials ----------------
__global__ void ktv_reduce(const float* __restrict__ part, unsigned short* __restrict__ M2t) {
    int idx = blockIdx.x * 256 + threadIdx.x;
    int bh = idx >> 14, rem = idx & 16383;
    const float* p = part + ((size_t)bh * 8) * 16384 + rem;
    float s = 0.f;
    #pragma unroll
    for (int k = 0; k < 8; ++k) s += p[(size_t)k * 16384];
    M2t[idx] = f2bf(s * 0.08838834764831845f);
}

// ---------------- W2 fold ----------------
__global__ __launch_bounds__(256) void w2_gemm(
    const unsigned short* __restrict__ Wo2, const unsigned short* __restrict__ M2t,
    unsigned short* __restrict__ W2)
{
    const int mt = blockIdx.x;
    const int bh = blockIdx.y;
    const int b = bh >> 4, h = bh & 15;
    const unsigned short* A = Wo2 + (size_t)(mt * 128) * DIMN + h * HD;
    const unsigned short* B = M2t + (size_t)bh * HD * HD;
    unsigned short* Cp = W2 + (size_t)b * DIMN * DIMN + (size_t)(mt * 128) * DIMN + h * HD;
    gemm_tile_core<1, 0>(A, DIMN, B, HD, nullptr, Cp, DIMN, HD);
}

extern "C" void kernel_launch(void* const* d_in, const int* in_sizes, int n_in,
                              void* d_out, int out_size, void* d_ws, size_t ws_size,
                              hipStream_t stream) {
    const float* x    = (const float*)d_in[0];
    const float* fcos = (const float*)d_in[1];
    const float* fsin = (const float*)d_in[2];
    const float* wq   = (const float*)d_in[3];
    const float* bq   = (const float*)d_in[4];
    const float* wk   = (const float*)d_in[5];
    const float* bk   = (const float*)d_in[6];
    const float* wv   = (const float*)d_in[7];
    const float* bv   = (const float*)d_in[8];
    const float* wo   = (const float*)d_in[9];
    const float* bo   = (const float*)d_in[10];
    float* out = (float*)d_out;

    char* ws = (char*)d_ws;
    size_t off = 0;
    auto alloc = [&](size_t bytes) { char* p = ws + off; off += (bytes + 255) & ~(size_t)255; return p; };

    unsigned short* Xb   = (unsigned short*)alloc((size_t)ROWS * DIMN * 2);
    unsigned short* Wcat = (unsigned short*)alloc((size_t)NQKV * DIMN * 2);
    unsigned short* Wo2  = (unsigned short*)alloc((size_t)DIMN * DIMN * 2);
    unsigned short* QKV  = (unsigned short*)alloc((size_t)ROWS * NQKV * 2);
    float*          part = (float*)alloc((size_t)32 * 8 * HD * HD * 4);
    unsigned short* M2t  = (unsigned short*)alloc((size_t)32 * HD * HD * 2);
    unsigned short* W2   = (unsigned short*)alloc((size_t)BSZ * DIMN * DIMN * 2);

    // all converts in one launch
    cvt_all<<<24576, 256, 0, stream>>>(x, wq, wk, wv, wo, Xb, Wcat, Wo2);

    // fused QKV projection + bias + RoPE  (M=4096, N=6144, K=2048): 32x48 = 1536 blocks
    gemm97<0><<<1536, 256, 0, stream>>>(
        Xb, DIMN, Wcat, DIMN, bq, bk, bv, fcos, fsin, QKV, NQKV, DIMN);

    // reassociated attention (no softmax): M2t = (K^T V)^T/sqrt(d) per (b,h)
    ktv_kernel<<<dim3(8, 32), 256, 0, stream>>>(QKV, part);
    ktv_reduce<<<(32 * 16384) / 256, 256, 0, stream>>>(part, M2t);

    // fold attention + output projection: W2_b = concat_h(Wo_h @ M2_{b,h})
    w2_gemm<<<dim3(16, 32), 256, 0, stream>>>(Wo2, M2t, W2);

    // out = Q @ W2_b^T + bo  (M=4096, N=2048 per batch, K=2048): 32x16 = 512 blocks
    gemm97<1><<<512, 256, 0, stream>>>(
        QKV, NQKV, W2, DIMN, bo, nullptr, nullptr, nullptr, nullptr, out, DIMN, DIMN);
}